// Round 1
// baseline (3545.289 us; speedup 1.0000x reference)
//
#include <hip/hip_runtime.h>
#include <math.h>

#define PI_F 3.14159265358979323846f

// ---------------------------------------------------------------------------
// Prep: softmax over sub-axis for C_syn_e / C_syn_i (also written to d_out),
// scaled-transposed copies CsT[e][s] = softmax * exp(scale[e]) for the einsum,
// and the 24x400 cos-basis table (exact inside-mask formula).
// ---------------------------------------------------------------------------
__global__ __launch_bounds__(256) void prep_kernel(
    const float* __restrict__ Ce_raw, const float* __restrict__ Ci_raw,
    const float* __restrict__ Escale, const float* __restrict__ Iscale,
    const float* __restrict__ temp,
    float* __restrict__ CsT_e, float* __restrict__ CsT_i,
    float* __restrict__ basis,
    float* __restrict__ outCe, float* __restrict__ outCi)
{
    int id = blockIdx.x * 256 + threadIdx.x;
    if (id < 2000) {
        int e = id;
        float t = temp[0];
        float v[20];
        float m = -1e30f;
        #pragma unroll
        for (int s = 0; s < 20; ++s) { v[s] = Ce_raw[s * 2000 + e] / t; m = fmaxf(m, v[s]); }
        float sum = 0.f;
        #pragma unroll
        for (int s = 0; s < 20; ++s) { v[s] = expf(v[s] - m); sum += v[s]; }
        float inv = 1.f / sum;
        float sc = expf(Escale[e]);
        #pragma unroll
        for (int s = 0; s < 20; ++s) {
            float p = v[s] * inv;
            outCe[s * 2000 + e] = p;
            CsT_e[e * 20 + s] = p * sc;
        }
    } else if (id < 2200) {
        int e = id - 2000;
        float t = temp[0];
        float v[20];
        float m = -1e30f;
        #pragma unroll
        for (int s = 0; s < 20; ++s) { v[s] = Ci_raw[s * 200 + e] / t; m = fmaxf(m, v[s]); }
        float sum = 0.f;
        #pragma unroll
        for (int s = 0; s < 20; ++s) { v[s] = expf(v[s] - m); sum += v[s]; }
        float inv = 1.f / sum;
        float sc = expf(Iscale[e]);
        #pragma unroll
        for (int s = 0; s < 20; ++s) {
            float p = v[s] * inv;
            outCi[s * 200 + e] = p;
            CsT_i[e * 20 + s] = p * sc;
        }
    } else if (id < 2200 + 24 * 400) {
        int idx = id - 2200;
        int j = idx / 400, d = idx - j * 400;
        float raw = 6.0f * logf((float)d + 1.0f + 1e-7f);
        float ph = (PI_F * 0.5f) * (float)j;
        float val = 0.f;
        if (raw >= ph - PI_F && raw <= ph + PI_F) val = 0.5f * cosf(raw - ph) + 0.5f;
        basis[idx] = val;
    }
}

// ---------------------------------------------------------------------------
// syn einsum: syn[b][s][t] = sum_e S[(b,t),e] * CsT[e][s]
// Block: 256 thr = 4 waves; wave w handles e-chunk w (uniform per wave ->
// CsT loads scalarize to s_load), lanes = 64 consecutive rows (b,t).
// Cross-wave reduction in LDS, stores coalesced per s.
// ---------------------------------------------------------------------------
template <int VEC>
__global__ __launch_bounds__(256) void syn_kernel(
    const float* __restrict__ S, const float* __restrict__ CsT,
    float* __restrict__ syn, int Eno, int echunk)
{
    __shared__ float red[4][64][21];
    const int lane = threadIdx.x & 63;
    int w = threadIdx.x >> 6;
    w = __builtin_amdgcn_readfirstlane(w);
    const int r = blockIdx.x * 64 + lane;   // grid sized so r < 40000 always

    float acc[20];
    #pragma unroll
    for (int s = 0; s < 20; ++s) acc[s] = 0.f;

    const int e0 = w * echunk;
    const float* Sr = S + (size_t)r * Eno + e0;

    for (int e = 0; e < echunk; e += VEC) {
        float v[VEC];
        if constexpr (VEC == 4) {
            float4 t4 = *reinterpret_cast<const float4*>(Sr + e);
            v[0] = t4.x; v[1] = t4.y; v[2] = t4.z; v[3] = t4.w;
        } else {
            float2 t2 = *reinterpret_cast<const float2*>(Sr + e);
            v[0] = t2.x; v[1] = t2.y;
        }
        #pragma unroll
        for (int q = 0; q < VEC; ++q) {
            const float4* ct = reinterpret_cast<const float4*>(CsT + (size_t)(e0 + e + q) * 20);
            float sv = v[q];
            #pragma unroll
            for (int c4 = 0; c4 < 5; ++c4) {
                float4 cc = ct[c4];
                acc[c4 * 4 + 0] = fmaf(sv, cc.x, acc[c4 * 4 + 0]);
                acc[c4 * 4 + 1] = fmaf(sv, cc.y, acc[c4 * 4 + 1]);
                acc[c4 * 4 + 2] = fmaf(sv, cc.z, acc[c4 * 4 + 2]);
                acc[c4 * 4 + 3] = fmaf(sv, cc.w, acc[c4 * 4 + 3]);
            }
        }
    }

    #pragma unroll
    for (int s = 0; s < 20; ++s) red[w][lane][s] = acc[s];
    __syncthreads();

    if (threadIdx.x < 64) {
        const int rr = blockIdx.x * 64 + threadIdx.x;
        const int b = rr / 5000;
        const int t = rr - b * 5000;
        #pragma unroll
        for (int s = 0; s < 20; ++s) {
            float a = red[0][threadIdx.x][s] + red[1][threadIdx.x][s]
                    + red[2][threadIdx.x][s] + red[3][threadIdx.x][s];
            syn[((size_t)b * 20 + s) * 5000 + t] = a;
        }
    }
}

// ---------------------------------------------------------------------------
// Fused basis-conv + layer1(tanh) + layer2 reduce.
// Support bounds widened by +-1 vs the analytic support; basis table holds
// exact-masked values (0 outside true support) so widening is exact.
// ---------------------------------------------------------------------------
constexpr int KLO[24] = {0,0,0,0,0,1,1,2,3,5,7,9,12,16,22,29,38,49,64,84,110,143,186,243};
constexpr int KHI[24] = {1,2,2,3,4,6,8,10,13,17,23,30,39,50,65,85,111,144,187,244,317,399,399,399};

template <int J>
__device__ __forceinline__ void conv_j(const float2* __restrict__ wp,
                                       const float* __restrict__ basis,
                                       const float* __restrict__ W_e,
                                       const float* __restrict__ W_i,
                                       int s, float (&z)[16][8])
{
    float be[8], bi[8];
    #pragma unroll
    for (int k = 0; k < 8; ++k) { be[k] = 0.f; bi[k] = 0.f; }
    #pragma unroll
    for (int d = KLO[J]; d <= KHI[J]; ++d) {
        float c = basis[J * 400 + d];            // uniform -> s_load
        #pragma unroll
        for (int k = 0; k < 8; ++k) {
            int m = 400 + k - d;                  // compile-time constant
            float2 v = wp[m + (m >> 3)];          // padded-swizzle LDS, CSE across (k,d)
            be[k] = fmaf(c, v.x, be[k]);
            bi[k] = fmaf(c, v.y, bi[k]);
        }
    }
    #pragma unroll
    for (int h = 0; h < 16; ++h) {
        float we = W_e[(s * 16 + h) * 24 + J];    // uniform -> s_load
        float wi = W_i[(s * 16 + h) * 24 + J];
        #pragma unroll
        for (int k = 0; k < 8; ++k)
            z[h][k] = fmaf(we, be[k], fmaf(wi, bi[k], z[h][k]));
    }
}

__global__ __launch_bounds__(128) void conv_kernel(
    const float* __restrict__ syn_e, const float* __restrict__ syn_i,
    const float* __restrict__ basis,
    const float* __restrict__ W_e, const float* __restrict__ W_i,
    const float* __restrict__ b1, const float* __restrict__ W2,
    float* __restrict__ sub_out)
{
    __shared__ float2 win[1602];                  // 1424 logical + pad every 8
    const int tid = threadIdx.x;
    const int tile = blockIdx.x, s = blockIdx.y, b = blockIdx.z;
    const int t0 = tile * 1024;

    const float* se = syn_e + ((size_t)b * 20 + s) * 5000;
    const float* si = syn_i + ((size_t)b * 20 + s) * 5000;
    for (int l = tid; l < 1424; l += 128) {
        int t = t0 - 400 + l;
        float ve = 0.f, vi = 0.f;
        if (t >= 0 && t < 5000) { ve = se[t]; vi = si[t]; }
        win[l + (l >> 3)] = make_float2(ve, vi);
    }
    __syncthreads();

    float z[16][8];
    #pragma unroll
    for (int h = 0; h < 16; ++h) {
        float bv = b1[s * 16 + h];
        #pragma unroll
        for (int k = 0; k < 8; ++k) z[h][k] = bv;
    }

    const float2* wp = win + 9 * tid;   // phys(l=8*tid+m) = 9*tid + m + (m>>3)

    conv_j<0>(wp, basis, W_e, W_i, s, z);  conv_j<1>(wp, basis, W_e, W_i, s, z);
    conv_j<2>(wp, basis, W_e, W_i, s, z);  conv_j<3>(wp, basis, W_e, W_i, s, z);
    conv_j<4>(wp, basis, W_e, W_i, s, z);  conv_j<5>(wp, basis, W_e, W_i, s, z);
    conv_j<6>(wp, basis, W_e, W_i, s, z);  conv_j<7>(wp, basis, W_e, W_i, s, z);
    conv_j<8>(wp, basis, W_e, W_i, s, z);  conv_j<9>(wp, basis, W_e, W_i, s, z);
    conv_j<10>(wp, basis, W_e, W_i, s, z); conv_j<11>(wp, basis, W_e, W_i, s, z);
    conv_j<12>(wp, basis, W_e, W_i, s, z); conv_j<13>(wp, basis, W_e, W_i, s, z);
    conv_j<14>(wp, basis, W_e, W_i, s, z); conv_j<15>(wp, basis, W_e, W_i, s, z);
    conv_j<16>(wp, basis, W_e, W_i, s, z); conv_j<17>(wp, basis, W_e, W_i, s, z);
    conv_j<18>(wp, basis, W_e, W_i, s, z); conv_j<19>(wp, basis, W_e, W_i, s, z);
    conv_j<20>(wp, basis, W_e, W_i, s, z); conv_j<21>(wp, basis, W_e, W_i, s, z);
    conv_j<22>(wp, basis, W_e, W_i, s, z); conv_j<23>(wp, basis, W_e, W_i, s, z);

    float w2v[16];
    #pragma unroll
    for (int h = 0; h < 16; ++h) w2v[h] = __expf(W2[s * 16 + h]);

    const int tbase = t0 + tid * 8;
    #pragma unroll
    for (int k = 0; k < 8; ++k) {
        int t = tbase + k;
        if (t < 5000) {
            float acc = 0.f;
            #pragma unroll
            for (int h = 0; h < 16; ++h) {
                float e2 = __expf(2.0f * z[h][k]);
                float th = 1.0f - 2.0f / (e2 + 1.0f);   // tanh, saturates correctly
                acc = fmaf(w2v[h], th, acc);
            }
            sub_out[((size_t)b * 5000 + t) * 20 + s] = acc;
        }
    }
}

// ---------------------------------------------------------------------------
// final[b,t] = V_o + sum_s sub_out[b,t,s]
// ---------------------------------------------------------------------------
__global__ __launch_bounds__(256) void final_kernel(
    const float* __restrict__ sub_out, const float* __restrict__ V_o,
    float* __restrict__ fin)
{
    int r = blockIdx.x * 256 + threadIdx.x;
    if (r < 40000) {
        const float* p = sub_out + (size_t)r * 20;
        float a = V_o[0];
        #pragma unroll
        for (int s = 0; s < 20; ++s) a += p[s];
        fin[r] = a;
    }
}

extern "C" void kernel_launch(void* const* d_in, const int* in_sizes, int n_in,
                              void* d_out, int out_size, void* d_ws, size_t ws_size,
                              hipStream_t stream)
{
    const float* S_e     = (const float*)d_in[0];
    const float* S_i     = (const float*)d_in[1];
    const float* E_scale = (const float*)d_in[2];
    const float* I_scale = (const float*)d_in[3];
    const float* W_e     = (const float*)d_in[4];
    const float* W_i     = (const float*)d_in[5];
    const float* W2      = (const float*)d_in[6];
    const float* b1      = (const float*)d_in[7];
    const float* Ce_raw  = (const float*)d_in[8];
    const float* Ci_raw  = (const float*)d_in[9];
    const float* V_o     = (const float*)d_in[10];
    const float* temp    = (const float*)d_in[11];
    // d_in[12] = T_no (400), d_in[13] = test (1) — fixed by the harness setup.

    float* out     = (float*)d_out;
    float* fin     = out;              // 40000
    float* sub_out = out + 40000;      // 800000
    float* outCe   = out + 840000;     // 40000
    float* outCi   = out + 880000;     // 4000

    float* ws    = (float*)d_ws;       // needs 6.62 MB
    float* CsT_e = ws;                 // 40000
    float* CsT_i = ws + 40000;         // 4000
    float* basis = ws + 44000;         // 9600
    float* syn_e = ws + 53600;         // 800000
    float* syn_i = ws + 853600;        // 800000

    prep_kernel<<<47, 256, 0, stream>>>(Ce_raw, Ci_raw, E_scale, I_scale, temp,
                                        CsT_e, CsT_i, basis, outCe, outCi);
    syn_kernel<4><<<625, 256, 0, stream>>>(S_e, CsT_e, syn_e, 2000, 500);
    syn_kernel<2><<<625, 256, 0, stream>>>(S_i, CsT_i, syn_i, 200, 50);
    conv_kernel<<<dim3(5, 20, 8), 128, 0, stream>>>(syn_e, syn_i, basis,
                                                    W_e, W_i, b1, W2, sub_out);
    final_kernel<<<157, 256, 0, stream>>>(sub_out, V_o, fin);
}

// Round 2
// 394.117 us; speedup vs baseline: 8.9955x; 8.9955x over previous
//
#include <hip/hip_runtime.h>
#include <math.h>

#define PI_F 3.14159265358979323846f
#define BSTRIDE 404   // basis row stride (400 taps + 4 zero pad for d-block alignment)

// ---------------------------------------------------------------------------
// Prep: softmax over sub-axis for C_syn_e / C_syn_i (also written to d_out),
// scaled-transposed copies CsT[e][s] = softmax * exp(scale[e]) for the einsum,
// and the 24x404 cos-basis table (exact inside-mask formula, zero-padded).
// ---------------------------------------------------------------------------
__global__ __launch_bounds__(256) void prep_kernel(
    const float* __restrict__ Ce_raw, const float* __restrict__ Ci_raw,
    const float* __restrict__ Escale, const float* __restrict__ Iscale,
    const float* __restrict__ temp,
    float* __restrict__ CsT_e, float* __restrict__ CsT_i,
    float* __restrict__ basis,
    float* __restrict__ outCe, float* __restrict__ outCi)
{
    int id = blockIdx.x * 256 + threadIdx.x;
    if (id < 2000) {
        int e = id;
        float t = temp[0];
        float v[20];
        float m = -1e30f;
        #pragma unroll
        for (int s = 0; s < 20; ++s) { v[s] = Ce_raw[s * 2000 + e] / t; m = fmaxf(m, v[s]); }
        float sum = 0.f;
        #pragma unroll
        for (int s = 0; s < 20; ++s) { v[s] = expf(v[s] - m); sum += v[s]; }
        float inv = 1.f / sum;
        float sc = expf(Escale[e]);
        #pragma unroll
        for (int s = 0; s < 20; ++s) {
            float p = v[s] * inv;
            outCe[s * 2000 + e] = p;
            CsT_e[e * 20 + s] = p * sc;
        }
    } else if (id < 2200) {
        int e = id - 2000;
        float t = temp[0];
        float v[20];
        float m = -1e30f;
        #pragma unroll
        for (int s = 0; s < 20; ++s) { v[s] = Ci_raw[s * 200 + e] / t; m = fmaxf(m, v[s]); }
        float sum = 0.f;
        #pragma unroll
        for (int s = 0; s < 20; ++s) { v[s] = expf(v[s] - m); sum += v[s]; }
        float inv = 1.f / sum;
        float sc = expf(Iscale[e]);
        #pragma unroll
        for (int s = 0; s < 20; ++s) {
            float p = v[s] * inv;
            outCi[s * 200 + e] = p;
            CsT_i[e * 20 + s] = p * sc;
        }
    } else if (id < 2200 + 24 * BSTRIDE) {
        int idx = id - 2200;
        int j = idx / BSTRIDE, d = idx - j * BSTRIDE;
        float val = 0.f;
        if (d < 400) {
            float raw = 6.0f * logf((float)d + 1.0f + 1e-7f);
            float ph = (PI_F * 0.5f) * (float)j;
            if (raw >= ph - PI_F && raw <= ph + PI_F) val = 0.5f * cosf(raw - ph) + 0.5f;
        }
        basis[idx] = val;
    }
}

// ---------------------------------------------------------------------------
// syn einsum: syn[b][s][t] = sum_e S[(b,t),e] * CsT[e][s]
// ---------------------------------------------------------------------------
template <int VEC>
__global__ __launch_bounds__(256) void syn_kernel(
    const float* __restrict__ S, const float* __restrict__ CsT,
    float* __restrict__ syn, int Eno, int echunk)
{
    __shared__ float red[4][64][21];
    const int lane = threadIdx.x & 63;
    int w = threadIdx.x >> 6;
    w = __builtin_amdgcn_readfirstlane(w);
    const int r = blockIdx.x * 64 + lane;

    float acc[20];
    #pragma unroll
    for (int s = 0; s < 20; ++s) acc[s] = 0.f;

    const int e0 = w * echunk;
    const float* Sr = S + (size_t)r * Eno + e0;

    for (int e = 0; e < echunk; e += VEC) {
        float v[VEC];
        if constexpr (VEC == 4) {
            float4 t4 = *reinterpret_cast<const float4*>(Sr + e);
            v[0] = t4.x; v[1] = t4.y; v[2] = t4.z; v[3] = t4.w;
        } else {
            float2 t2 = *reinterpret_cast<const float2*>(Sr + e);
            v[0] = t2.x; v[1] = t2.y;
        }
        #pragma unroll
        for (int q = 0; q < VEC; ++q) {
            const float4* ct = reinterpret_cast<const float4*>(CsT + (size_t)(e0 + e + q) * 20);
            float sv = v[q];
            #pragma unroll
            for (int c4 = 0; c4 < 5; ++c4) {
                float4 cc = ct[c4];
                acc[c4 * 4 + 0] = fmaf(sv, cc.x, acc[c4 * 4 + 0]);
                acc[c4 * 4 + 1] = fmaf(sv, cc.y, acc[c4 * 4 + 1]);
                acc[c4 * 4 + 2] = fmaf(sv, cc.z, acc[c4 * 4 + 2]);
                acc[c4 * 4 + 3] = fmaf(sv, cc.w, acc[c4 * 4 + 3]);
            }
        }
    }

    #pragma unroll
    for (int s = 0; s < 20; ++s) red[w][lane][s] = acc[s];
    __syncthreads();

    if (threadIdx.x < 64) {
        const int rr = blockIdx.x * 64 + threadIdx.x;
        const int b = rr / 5000;
        const int t = rr - b * 5000;
        #pragma unroll
        for (int s = 0; s < 20; ++s) {
            float a = red[0][threadIdx.x][s] + red[1][threadIdx.x][s]
                    + red[2][threadIdx.x][s] + red[3][threadIdx.x][s];
            syn[((size_t)b * 20 + s) * 5000 + t] = a;
        }
    }
}

// ---------------------------------------------------------------------------
// Fused basis-conv + layer1(tanh) + layer2 reduce. Loop-based (no giant
// unroll): thread owns 4 consecutive t; d-loop in blocks of 4 taps with a
// sliding 4xfloat4 register window (2 new ds_read_b128 per block).
// LDS window in 16B granules with g+(g>>3) swizzle -> conflict-free b128.
// Support bounds widened to 4-aligned ranges; basis table is exact-masked
// (zero outside true support, zero pad at 400..403) so widening is exact.
// ---------------------------------------------------------------------------
__device__ const int CJ_LO[24] = {0,0,0,0,0,0,0,0,0,4,4,8,12,16,20,28,36,48,64,84,108,140,184,240};
__device__ const int CJ_NB[24] = {1,1,1,1,2,2,3,3,4,4,5,6,7,9,12,15,19,25,31,41,53,65,54,40};

__global__ __launch_bounds__(256, 2) void conv_kernel(
    const float* __restrict__ syn_e, const float* __restrict__ syn_i,
    const float* __restrict__ basis,
    const float* __restrict__ W_e, const float* __restrict__ W_i,
    const float* __restrict__ b1, const float* __restrict__ W2,
    float* __restrict__ sub_out)
{
    __shared__ float4 win4[804];                 // 714 granules + swizzle pad
    float2* win2 = reinterpret_cast<float2*>(win4);
    const int tid = threadIdx.x;
    const int tile = blockIdx.x, s = blockIdx.y, bz = blockIdx.z;
    const int t0 = tile * 1024;

    // window: logical float2 index l (0..1427) holds (syn_e, syn_i) at
    // t = t0 - 404 + l; granule g = l>>1 stored at phys g + (g>>3).
    const float* se = syn_e + ((size_t)bz * 20 + s) * 5000;
    const float* si = syn_i + ((size_t)bz * 20 + s) * 5000;
    for (int l = tid; l < 1428; l += 256) {
        int t = t0 - 404 + l;
        float ve = 0.f, vi = 0.f;
        if ((unsigned)t < 5000u) { ve = se[t]; vi = si[t]; }
        int g = l >> 1;
        win2[2 * (g + (g >> 3)) + (l & 1)] = make_float2(ve, vi);
    }
    __syncthreads();

    float z[16][4];
    #pragma unroll
    for (int h = 0; h < 16; ++h) {
        float bv = b1[s * 16 + h];
        #pragma unroll
        for (int k = 0; k < 4; ++k) z[h][k] = bv;
    }

    const int base = 4 * tid + 400;              // window l of t = t0+4*tid

    for (int j = 0; j < 24; ++j) {
        const float* bj = basis + j * BSTRIDE;
        const int lo = CJ_LO[j];
        const int nb = CJ_NB[j];
        float be0 = 0.f, be1 = 0.f, be2 = 0.f, be3 = 0.f;
        float bi0 = 0.f, bi1 = 0.f, bi2 = 0.f, bi3 = 0.f;

        int g = (base - lo) >> 1;                // even; granules g..g+3 = l S..S+7
        float4 V0 = win4[g + (g >> 3)];
        float4 V1 = win4[(g + 1) + ((g + 1) >> 3)];
        float4 V2 = win4[(g + 2) + ((g + 2) >> 3)];
        float4 V3 = win4[(g + 3) + ((g + 3) >> 3)];

        int d0 = lo;
        for (int bb = 0; bb < nb; ++bb) {
            // taps d0..d0+3 for k=0..3: value index jj=4+k-dd, l=S+jj
            // granule float4 = (e@l_even, i@l_even, e@l_odd, i@l_odd)
            float c0 = bj[d0], c1 = bj[d0 + 1], c2 = bj[d0 + 2], c3 = bj[d0 + 3];
            // dd=0: jj=4,5,6,7
            be0 = fmaf(c0, V2.x, be0); bi0 = fmaf(c0, V2.y, bi0);
            be1 = fmaf(c0, V2.z, be1); bi1 = fmaf(c0, V2.w, bi1);
            be2 = fmaf(c0, V3.x, be2); bi2 = fmaf(c0, V3.y, bi2);
            be3 = fmaf(c0, V3.z, be3); bi3 = fmaf(c0, V3.w, bi3);
            // dd=1: jj=3,4,5,6
            be0 = fmaf(c1, V1.z, be0); bi0 = fmaf(c1, V1.w, bi0);
            be1 = fmaf(c1, V2.x, be1); bi1 = fmaf(c1, V2.y, bi1);
            be2 = fmaf(c1, V2.z, be2); bi2 = fmaf(c1, V2.w, bi2);
            be3 = fmaf(c1, V3.x, be3); bi3 = fmaf(c1, V3.y, bi3);
            // dd=2: jj=2,3,4,5
            be0 = fmaf(c2, V1.x, be0); bi0 = fmaf(c2, V1.y, bi0);
            be1 = fmaf(c2, V1.z, be1); bi1 = fmaf(c2, V1.w, bi1);
            be2 = fmaf(c2, V2.x, be2); bi2 = fmaf(c2, V2.y, bi2);
            be3 = fmaf(c2, V2.z, be3); bi3 = fmaf(c2, V2.w, bi3);
            // dd=3: jj=1,2,3,4
            be0 = fmaf(c3, V0.z, be0); bi0 = fmaf(c3, V0.w, bi0);
            be1 = fmaf(c3, V1.x, be1); bi1 = fmaf(c3, V1.y, bi1);
            be2 = fmaf(c3, V1.z, be2); bi2 = fmaf(c3, V1.w, bi2);
            be3 = fmaf(c3, V2.x, be3); bi3 = fmaf(c3, V2.y, bi3);
            // slide window: next block needs granules g-2..g+1
            d0 += 4;
            V3 = V1; V2 = V0;
            g -= 2;
            V0 = win4[g + (g >> 3)];
            V1 = win4[(g + 1) + ((g + 1) >> 3)];
        }

        #pragma unroll
        for (int h = 0; h < 16; ++h) {
            float we = W_e[(s * 16 + h) * 24 + j];   // uniform -> s_load
            float wi = W_i[(s * 16 + h) * 24 + j];
            z[h][0] = fmaf(we, be0, fmaf(wi, bi0, z[h][0]));
            z[h][1] = fmaf(we, be1, fmaf(wi, bi1, z[h][1]));
            z[h][2] = fmaf(we, be2, fmaf(wi, bi2, z[h][2]));
            z[h][3] = fmaf(we, be3, fmaf(wi, bi3, z[h][3]));
        }
    }

    float w2v[16];
    #pragma unroll
    for (int h = 0; h < 16; ++h) w2v[h] = __expf(W2[s * 16 + h]);

    #pragma unroll
    for (int k = 0; k < 4; ++k) {
        int t = t0 + 4 * tid + k;
        if (t < 5000) {
            float acc = 0.f;
            #pragma unroll
            for (int h = 0; h < 16; ++h) {
                float e2 = __expf(2.0f * z[h][k]);
                float th = 1.0f - 2.0f / (e2 + 1.0f);   // tanh, saturates correctly
                acc = fmaf(w2v[h], th, acc);
            }
            sub_out[((size_t)bz * 5000 + t) * 20 + s] = acc;
        }
    }
}

// ---------------------------------------------------------------------------
// final[b,t] = V_o + sum_s sub_out[b,t,s]
// ---------------------------------------------------------------------------
__global__ __launch_bounds__(256) void final_kernel(
    const float* __restrict__ sub_out, const float* __restrict__ V_o,
    float* __restrict__ fin)
{
    int r = blockIdx.x * 256 + threadIdx.x;
    if (r < 40000) {
        const float* p = sub_out + (size_t)r * 20;
        float a = V_o[0];
        #pragma unroll
        for (int s = 0; s < 20; ++s) a += p[s];
        fin[r] = a;
    }
}

extern "C" void kernel_launch(void* const* d_in, const int* in_sizes, int n_in,
                              void* d_out, int out_size, void* d_ws, size_t ws_size,
                              hipStream_t stream)
{
    const float* S_e     = (const float*)d_in[0];
    const float* S_i     = (const float*)d_in[1];
    const float* E_scale = (const float*)d_in[2];
    const float* I_scale = (const float*)d_in[3];
    const float* W_e     = (const float*)d_in[4];
    const float* W_i     = (const float*)d_in[5];
    const float* W2      = (const float*)d_in[6];
    const float* b1      = (const float*)d_in[7];
    const float* Ce_raw  = (const float*)d_in[8];
    const float* Ci_raw  = (const float*)d_in[9];
    const float* V_o     = (const float*)d_in[10];
    const float* temp    = (const float*)d_in[11];

    float* out     = (float*)d_out;
    float* fin     = out;              // 40000
    float* sub_out = out + 40000;      // 800000
    float* outCe   = out + 840000;     // 40000
    float* outCi   = out + 880000;     // 4000

    float* ws    = (float*)d_ws;
    float* CsT_e = ws;                 // 40000
    float* CsT_i = ws + 40000;         // 4000
    float* basis = ws + 44000;         // 24*404 = 9696
    float* syn_e = ws + 53696;         // 800000
    float* syn_i = ws + 853696;        // 800000

    prep_kernel<<<47, 256, 0, stream>>>(Ce_raw, Ci_raw, E_scale, I_scale, temp,
                                        CsT_e, CsT_i, basis, outCe, outCi);
    syn_kernel<4><<<625, 256, 0, stream>>>(S_e, CsT_e, syn_e, 2000, 500);
    syn_kernel<2><<<625, 256, 0, stream>>>(S_i, CsT_i, syn_i, 200, 50);
    conv_kernel<<<dim3(5, 20, 8), 256, 0, stream>>>(syn_e, syn_i, basis,
                                                    W_e, W_i, b1, W2, sub_out);
    final_kernel<<<157, 256, 0, stream>>>(sub_out, V_o, fin);
}

// Round 3
// 336.383 us; speedup vs baseline: 10.5394x; 1.1716x over previous
//
#include <hip/hip_runtime.h>
#include <math.h>

#define PI_F 3.14159265358979323846f
#define BSTRIDE 404   // basis row stride (400 taps + 4 zero pad)

// ---------------------------------------------------------------------------
// Prep: softmax over sub-axis (also to d_out), scaled-transposed CsT copies
// (zero-padded to 2048 / 256 rows), and the 24x404 masked cos-basis table.
// ---------------------------------------------------------------------------
__global__ __launch_bounds__(256) void prep_kernel(
    const float* __restrict__ Ce_raw, const float* __restrict__ Ci_raw,
    const float* __restrict__ Escale, const float* __restrict__ Iscale,
    const float* __restrict__ temp,
    float* __restrict__ CsT_e, float* __restrict__ CsT_i,
    float* __restrict__ basis,
    float* __restrict__ outCe, float* __restrict__ outCi)
{
    int id = blockIdx.x * 256 + threadIdx.x;
    if (id < 2000) {
        int e = id;
        float t = temp[0];
        float v[20];
        float m = -1e30f;
        #pragma unroll
        for (int s = 0; s < 20; ++s) { v[s] = Ce_raw[s * 2000 + e] / t; m = fmaxf(m, v[s]); }
        float sum = 0.f;
        #pragma unroll
        for (int s = 0; s < 20; ++s) { v[s] = expf(v[s] - m); sum += v[s]; }
        float inv = 1.f / sum;
        float sc = expf(Escale[e]);
        #pragma unroll
        for (int s = 0; s < 20; ++s) {
            float p = v[s] * inv;
            outCe[s * 2000 + e] = p;
            CsT_e[e * 20 + s] = p * sc;
        }
    } else if (id < 2200) {
        int e = id - 2000;
        float t = temp[0];
        float v[20];
        float m = -1e30f;
        #pragma unroll
        for (int s = 0; s < 20; ++s) { v[s] = Ci_raw[s * 200 + e] / t; m = fmaxf(m, v[s]); }
        float sum = 0.f;
        #pragma unroll
        for (int s = 0; s < 20; ++s) { v[s] = expf(v[s] - m); sum += v[s]; }
        float inv = 1.f / sum;
        float sc = expf(Iscale[e]);
        #pragma unroll
        for (int s = 0; s < 20; ++s) {
            float p = v[s] * inv;
            outCi[s * 200 + e] = p;
            CsT_i[e * 20 + s] = p * sc;
        }
    } else if (id < 2200 + 24 * BSTRIDE) {
        int idx = id - 2200;
        int j = idx / BSTRIDE, d = idx - j * BSTRIDE;
        float val = 0.f;
        if (d < 400) {
            float raw = 6.0f * logf((float)d + 1.0f + 1e-7f);
            float ph = (PI_F * 0.5f) * (float)j;
            if (raw >= ph - PI_F && raw <= ph + PI_F) val = 0.5f * cosf(raw - ph) + 0.5f;
        }
        basis[idx] = val;
    } else if (id < 11896 + 48) {               // CsT_e pad rows 2000..2047
        int row = 2000 + (id - 11896);
        #pragma unroll
        for (int s = 0; s < 20; ++s) CsT_e[row * 20 + s] = 0.f;
    } else if (id < 11944 + 56) {               // CsT_i pad rows 200..255
        int row = 200 + (id - 11944);
        #pragma unroll
        for (int s = 0; s < 20; ++s) CsT_i[row * 20 + s] = 0.f;
    }
}

// ---------------------------------------------------------------------------
// syn einsum, LDS-staged: block = 64 rows x all e. Per 128-e chunk: coalesced
// float4 loads (lanes along e) -> padded LDS tile; wave w computes a
// wave-uniform 32-e quarter (CsT scalarizes to s_load), lane -> row.
// 4 partials per row reduced through LDS (aliased over the tile).
// ---------------------------------------------------------------------------
template <int NCHUNK>
__global__ __launch_bounds__(256) void syn_kernel(
    const float* __restrict__ S, const float* __restrict__ CsT,
    float* __restrict__ syn, int Eno)
{
    __shared__ float4 tile[64 * 33];                       // 33792 B
    float* red = reinterpret_cast<float*>(tile);           // [64][4][20] alias
    const int tid = threadIdx.x;
    const int lane = tid & 63;
    const int w = __builtin_amdgcn_readfirstlane(tid >> 6);
    const int r0 = blockIdx.x * 64;

    float acc[20];
    #pragma unroll
    for (int s = 0; s < 20; ++s) acc[s] = 0.f;

    for (int ch = 0; ch < NCHUNK; ++ch) {
        const int ebase = ch * 128;
        #pragma unroll
        for (int i = 0; i < 8; ++i) {
            int f = tid + i * 256;
            int row = f >> 5, col4 = f & 31;
            int e0 = ebase + col4 * 4;
            float4 v = make_float4(0.f, 0.f, 0.f, 0.f);
            if (e0 + 4 <= Eno)
                v = *reinterpret_cast<const float4*>(S + (size_t)(r0 + row) * Eno + e0);
            tile[row * 33 + col4] = v;
        }
        __syncthreads();

        const float4* crow = reinterpret_cast<const float4*>(CsT + (size_t)(ebase + w * 32) * 20);
        #pragma unroll
        for (int c4 = 0; c4 < 8; ++c4) {
            float4 v = tile[lane * 33 + w * 8 + c4];
            const float4* ct = crow + c4 * 20;             // 4 e-rows x 5 float4
            float vv[4] = {v.x, v.y, v.z, v.w};
            #pragma unroll
            for (int q = 0; q < 4; ++q) {
                float sv = vv[q];
                #pragma unroll
                for (int c5 = 0; c5 < 5; ++c5) {
                    float4 cc = ct[q * 5 + c5];
                    acc[c5 * 4 + 0] = fmaf(sv, cc.x, acc[c5 * 4 + 0]);
                    acc[c5 * 4 + 1] = fmaf(sv, cc.y, acc[c5 * 4 + 1]);
                    acc[c5 * 4 + 2] = fmaf(sv, cc.z, acc[c5 * 4 + 2]);
                    acc[c5 * 4 + 3] = fmaf(sv, cc.w, acc[c5 * 4 + 3]);
                }
            }
        }
        __syncthreads();
    }

    #pragma unroll
    for (int s = 0; s < 20; ++s) red[(lane * 4 + w) * 20 + s] = acc[s];
    __syncthreads();

    #pragma unroll
    for (int i = 0; i < 5; ++i) {                          // p = s*64 + row
        int p = tid + i * 256;
        int row = p & 63, s = p >> 6;
        float a = red[(row * 4 + 0) * 20 + s] + red[(row * 4 + 1) * 20 + s]
                + red[(row * 4 + 2) * 20 + s] + red[(row * 4 + 3) * 20 + s];
        int r = r0 + row;
        int b = r / 5000, t = r - b * 5000;
        syn[((size_t)b * 20 + s) * 5000 + t] = a;          // coalesced per s
    }
}

// ---------------------------------------------------------------------------
// Fused basis-conv + layer1(tanh) + layer2 reduce. Sliding 4xfloat4 register
// window over padded-granule LDS; basis coefficients prefetched one tap-block
// ahead as float4 (pad granule keeps the prefetch in-bounds).
// ---------------------------------------------------------------------------
__device__ const int CJ_LO[24] = {0,0,0,0,0,0,0,0,0,4,4,8,12,16,20,28,36,48,64,84,108,140,184,240};
__device__ const int CJ_NB[24] = {1,1,1,1,2,2,3,3,4,4,5,6,7,9,12,15,19,25,31,41,53,65,54,40};

__global__ __launch_bounds__(256) void conv_kernel(
    const float* __restrict__ syn_e, const float* __restrict__ syn_i,
    const float* __restrict__ basis,
    const float* __restrict__ W_e, const float* __restrict__ W_i,
    const float* __restrict__ b1, const float* __restrict__ W2,
    float* __restrict__ sub_out)
{
    __shared__ float4 win4[804];
    float2* win2 = reinterpret_cast<float2*>(win4);
    const int tid = threadIdx.x;
    const int tile = blockIdx.x, s = blockIdx.y, bz = blockIdx.z;
    const int t0 = tile * 1024;

    const float* se = syn_e + ((size_t)bz * 20 + s) * 5000;
    const float* si = syn_i + ((size_t)bz * 20 + s) * 5000;
    for (int l = tid; l < 1428; l += 256) {
        int t = t0 - 404 + l;
        float ve = 0.f, vi = 0.f;
        if ((unsigned)t < 5000u) { ve = se[t]; vi = si[t]; }
        int g = l >> 1;
        win2[2 * (g + (g >> 3)) + (l & 1)] = make_float2(ve, vi);
    }
    __syncthreads();

    float z[16][4];
    #pragma unroll
    for (int h = 0; h < 16; ++h) {
        float bv = b1[s * 16 + h];
        #pragma unroll
        for (int k = 0; k < 4; ++k) z[h][k] = bv;
    }

    const int base = 4 * tid + 400;

    for (int j = 0; j < 24; ++j) {
        const float4* bj4 = reinterpret_cast<const float4*>(basis + j * BSTRIDE);
        const int lo = CJ_LO[j];
        const int nb = CJ_NB[j];
        float be0 = 0.f, be1 = 0.f, be2 = 0.f, be3 = 0.f;
        float bi0 = 0.f, bi1 = 0.f, bi2 = 0.f, bi3 = 0.f;

        int g = (base - lo) >> 1;
        float4 V0 = win4[g + (g >> 3)];
        float4 V1 = win4[(g + 1) + ((g + 1) >> 3)];
        float4 V2 = win4[(g + 2) + ((g + 2) >> 3)];
        float4 V3 = win4[(g + 3) + ((g + 3) >> 3)];
        float4 C = bj4[lo >> 2];

        for (int bb = 0; bb < nb; ++bb) {
            float4 Cn = bj4[(lo >> 2) + bb + 1];   // pad granule -> in-bounds
            // dd=0: jj=4,5,6,7
            be0 = fmaf(C.x, V2.x, be0); bi0 = fmaf(C.x, V2.y, bi0);
            be1 = fmaf(C.x, V2.z, be1); bi1 = fmaf(C.x, V2.w, bi1);
            be2 = fmaf(C.x, V3.x, be2); bi2 = fmaf(C.x, V3.y, bi2);
            be3 = fmaf(C.x, V3.z, be3); bi3 = fmaf(C.x, V3.w, bi3);
            // dd=1: jj=3,4,5,6
            be0 = fmaf(C.y, V1.z, be0); bi0 = fmaf(C.y, V1.w, bi0);
            be1 = fmaf(C.y, V2.x, be1); bi1 = fmaf(C.y, V2.y, bi1);
            be2 = fmaf(C.y, V2.z, be2); bi2 = fmaf(C.y, V2.w, bi2);
            be3 = fmaf(C.y, V3.x, be3); bi3 = fmaf(C.y, V3.y, bi3);
            // dd=2: jj=2,3,4,5
            be0 = fmaf(C.z, V1.x, be0); bi0 = fmaf(C.z, V1.y, bi0);
            be1 = fmaf(C.z, V1.z, be1); bi1 = fmaf(C.z, V1.w, bi1);
            be2 = fmaf(C.z, V2.x, be2); bi2 = fmaf(C.z, V2.y, bi2);
            be3 = fmaf(C.z, V2.z, be3); bi3 = fmaf(C.z, V2.w, bi3);
            // dd=3: jj=1,2,3,4
            be0 = fmaf(C.w, V0.z, be0); bi0 = fmaf(C.w, V0.w, bi0);
            be1 = fmaf(C.w, V1.x, be1); bi1 = fmaf(C.w, V1.y, bi1);
            be2 = fmaf(C.w, V1.z, be2); bi2 = fmaf(C.w, V1.w, bi2);
            be3 = fmaf(C.w, V2.x, be3); bi3 = fmaf(C.w, V2.y, bi3);
            V3 = V1; V2 = V0;
            g -= 2;
            V0 = win4[g + (g >> 3)];
            V1 = win4[(g + 1) + ((g + 1) >> 3)];
            C = Cn;
        }

        #pragma unroll
        for (int h = 0; h < 16; ++h) {
            float we = W_e[(s * 16 + h) * 24 + j];
            float wi = W_i[(s * 16 + h) * 24 + j];
            z[h][0] = fmaf(we, be0, fmaf(wi, bi0, z[h][0]));
            z[h][1] = fmaf(we, be1, fmaf(wi, bi1, z[h][1]));
            z[h][2] = fmaf(we, be2, fmaf(wi, bi2, z[h][2]));
            z[h][3] = fmaf(we, be3, fmaf(wi, bi3, z[h][3]));
        }
    }

    float w2v[16];
    #pragma unroll
    for (int h = 0; h < 16; ++h) w2v[h] = __expf(W2[s * 16 + h]);

    #pragma unroll
    for (int k = 0; k < 4; ++k) {
        int t = t0 + 4 * tid + k;
        if (t < 5000) {
            float acc = 0.f;
            #pragma unroll
            for (int h = 0; h < 16; ++h) {
                float e2 = __expf(2.0f * z[h][k]);
                float th = 1.0f - 2.0f / (e2 + 1.0f);
                acc = fmaf(w2v[h], th, acc);
            }
            sub_out[((size_t)bz * 5000 + t) * 20 + s] = acc;
        }
    }
}

// ---------------------------------------------------------------------------
// final[b,t] = V_o + sum_s sub_out[b,t,s]
// ---------------------------------------------------------------------------
__global__ __launch_bounds__(256) void final_kernel(
    const float* __restrict__ sub_out, const float* __restrict__ V_o,
    float* __restrict__ fin)
{
    int r = blockIdx.x * 256 + threadIdx.x;
    if (r < 40000) {
        const float* p = sub_out + (size_t)r * 20;
        float a = V_o[0];
        #pragma unroll
        for (int s = 0; s < 20; ++s) a += p[s];
        fin[r] = a;
    }
}

extern "C" void kernel_launch(void* const* d_in, const int* in_sizes, int n_in,
                              void* d_out, int out_size, void* d_ws, size_t ws_size,
                              hipStream_t stream)
{
    const float* S_e     = (const float*)d_in[0];
    const float* S_i     = (const float*)d_in[1];
    const float* E_scale = (const float*)d_in[2];
    const float* I_scale = (const float*)d_in[3];
    const float* W_e     = (const float*)d_in[4];
    const float* W_i     = (const float*)d_in[5];
    const float* W2      = (const float*)d_in[6];
    const float* b1      = (const float*)d_in[7];
    const float* Ce_raw  = (const float*)d_in[8];
    const float* Ci_raw  = (const float*)d_in[9];
    const float* V_o     = (const float*)d_in[10];
    const float* temp    = (const float*)d_in[11];

    float* out     = (float*)d_out;
    float* fin     = out;              // 40000
    float* sub_out = out + 40000;      // 800000
    float* outCe   = out + 840000;     // 40000
    float* outCi   = out + 880000;     // 4000

    float* ws    = (float*)d_ws;
    float* CsT_e = ws;                 // 2048*20 = 40960 (zero-padded)
    float* CsT_i = ws + 40960;         // 256*20  = 5120  (zero-padded)
    float* basis = ws + 46080;         // 24*404  = 9696
    float* syn_e = ws + 55776;         // 800000
    float* syn_i = ws + 855776;        // 800000

    prep_kernel<<<47, 256, 0, stream>>>(Ce_raw, Ci_raw, E_scale, I_scale, temp,
                                        CsT_e, CsT_i, basis, outCe, outCi);
    syn_kernel<16><<<625, 256, 0, stream>>>(S_e, CsT_e, syn_e, 2000);
    syn_kernel<2><<<625, 256, 0, stream>>>(S_i, CsT_i, syn_i, 200);
    conv_kernel<<<dim3(5, 20, 8), 256, 0, stream>>>(syn_e, syn_i, basis,
                                                    W_e, W_i, b1, W2, sub_out);
    final_kernel<<<157, 256, 0, stream>>>(sub_out, V_o, fin);
}

// Round 4
// 289.142 us; speedup vs baseline: 12.2614x; 1.1634x over previous
//
#include <hip/hip_runtime.h>
#include <math.h>

#define PI_F 3.14159265358979323846f
#define BSTRIDE 404   // basis row stride (400 taps + 4 zero pad)

// ---------------------------------------------------------------------------
// Prep: softmax over sub-axis (also to d_out), scaled-transposed CsT copies
// (zero-padded to 2048 / 256 rows), and the 24x404 masked cos-basis table.
// ---------------------------------------------------------------------------
__global__ __launch_bounds__(256) void prep_kernel(
    const float* __restrict__ Ce_raw, const float* __restrict__ Ci_raw,
    const float* __restrict__ Escale, const float* __restrict__ Iscale,
    const float* __restrict__ temp,
    float* __restrict__ CsT_e, float* __restrict__ CsT_i,
    float* __restrict__ basis,
    float* __restrict__ outCe, float* __restrict__ outCi)
{
    int id = blockIdx.x * 256 + threadIdx.x;
    if (id < 2000) {
        int e = id;
        float t = temp[0];
        float v[20];
        float m = -1e30f;
        #pragma unroll
        for (int s = 0; s < 20; ++s) { v[s] = Ce_raw[s * 2000 + e] / t; m = fmaxf(m, v[s]); }
        float sum = 0.f;
        #pragma unroll
        for (int s = 0; s < 20; ++s) { v[s] = expf(v[s] - m); sum += v[s]; }
        float inv = 1.f / sum;
        float sc = expf(Escale[e]);
        #pragma unroll
        for (int s = 0; s < 20; ++s) {
            float p = v[s] * inv;
            outCe[s * 2000 + e] = p;
            CsT_e[e * 20 + s] = p * sc;
        }
    } else if (id < 2200) {
        int e = id - 2000;
        float t = temp[0];
        float v[20];
        float m = -1e30f;
        #pragma unroll
        for (int s = 0; s < 20; ++s) { v[s] = Ci_raw[s * 200 + e] / t; m = fmaxf(m, v[s]); }
        float sum = 0.f;
        #pragma unroll
        for (int s = 0; s < 20; ++s) { v[s] = expf(v[s] - m); sum += v[s]; }
        float inv = 1.f / sum;
        float sc = expf(Iscale[e]);
        #pragma unroll
        for (int s = 0; s < 20; ++s) {
            float p = v[s] * inv;
            outCi[s * 200 + e] = p;
            CsT_i[e * 20 + s] = p * sc;
        }
    } else if (id < 2200 + 24 * BSTRIDE) {
        int idx = id - 2200;
        int j = idx / BSTRIDE, d = idx - j * BSTRIDE;
        float val = 0.f;
        if (d < 400) {
            float raw = 6.0f * logf((float)d + 1.0f + 1e-7f);
            float ph = (PI_F * 0.5f) * (float)j;
            if (raw >= ph - PI_F && raw <= ph + PI_F) val = 0.5f * cosf(raw - ph) + 0.5f;
        }
        basis[idx] = val;
    } else if (id < 11896 + 48) {               // CsT_e pad rows 2000..2047
        int row = 2000 + (id - 11896);
        #pragma unroll
        for (int s = 0; s < 20; ++s) CsT_e[row * 20 + s] = 0.f;
    } else if (id < 11944 + 56) {               // CsT_i pad rows 200..255
        int row = 200 + (id - 11944);
        #pragma unroll
        for (int s = 0; s < 20; ++s) CsT_i[row * 20 + s] = 0.f;
    }
}

// ---------------------------------------------------------------------------
// syn einsum, LDS-staged: block = 64 rows x all e. Per 128-e chunk: coalesced
// float4 loads (lanes along e) -> padded LDS tile; wave w computes a
// wave-uniform 32-e quarter (CsT scalarizes to s_load), lane -> row.
// ---------------------------------------------------------------------------
template <int NCHUNK>
__global__ __launch_bounds__(256) void syn_kernel(
    const float* __restrict__ S, const float* __restrict__ CsT,
    float* __restrict__ syn, int Eno)
{
    __shared__ float4 tile[64 * 33];                       // 33792 B
    float* red = reinterpret_cast<float*>(tile);           // [64][4][20] alias
    const int tid = threadIdx.x;
    const int lane = tid & 63;
    const int w = __builtin_amdgcn_readfirstlane(tid >> 6);
    const int r0 = blockIdx.x * 64;

    float acc[20];
    #pragma unroll
    for (int s = 0; s < 20; ++s) acc[s] = 0.f;

    for (int ch = 0; ch < NCHUNK; ++ch) {
        const int ebase = ch * 128;
        #pragma unroll
        for (int i = 0; i < 8; ++i) {
            int f = tid + i * 256;
            int row = f >> 5, col4 = f & 31;
            int e0 = ebase + col4 * 4;
            float4 v = make_float4(0.f, 0.f, 0.f, 0.f);
            if (e0 + 4 <= Eno)
                v = *reinterpret_cast<const float4*>(S + (size_t)(r0 + row) * Eno + e0);
            tile[row * 33 + col4] = v;
        }
        __syncthreads();

        const float4* crow = reinterpret_cast<const float4*>(CsT + (size_t)(ebase + w * 32) * 20);
        #pragma unroll
        for (int c4 = 0; c4 < 8; ++c4) {
            float4 v = tile[lane * 33 + w * 8 + c4];
            const float4* ct = crow + c4 * 20;             // 4 e-rows x 5 float4
            float vv[4] = {v.x, v.y, v.z, v.w};
            #pragma unroll
            for (int q = 0; q < 4; ++q) {
                float sv = vv[q];
                #pragma unroll
                for (int c5 = 0; c5 < 5; ++c5) {
                    float4 cc = ct[q * 5 + c5];
                    acc[c5 * 4 + 0] = fmaf(sv, cc.x, acc[c5 * 4 + 0]);
                    acc[c5 * 4 + 1] = fmaf(sv, cc.y, acc[c5 * 4 + 1]);
                    acc[c5 * 4 + 2] = fmaf(sv, cc.z, acc[c5 * 4 + 2]);
                    acc[c5 * 4 + 3] = fmaf(sv, cc.w, acc[c5 * 4 + 3]);
                }
            }
        }
        __syncthreads();
    }

    #pragma unroll
    for (int s = 0; s < 20; ++s) red[(lane * 4 + w) * 20 + s] = acc[s];
    __syncthreads();

    #pragma unroll
    for (int i = 0; i < 5; ++i) {                          // p = s*64 + row
        int p = tid + i * 256;
        int row = p & 63, s = p >> 6;
        float a = red[(row * 4 + 0) * 20 + s] + red[(row * 4 + 1) * 20 + s]
                + red[(row * 4 + 2) * 20 + s] + red[(row * 4 + 3) * 20 + s];
        int r = r0 + row;
        int b = r / 5000, t = r - b * 5000;
        syn[((size_t)b * 20 + s) * 5000 + t] = a;          // coalesced per s
    }
}

// ---------------------------------------------------------------------------
// Fused basis-conv + layer1(tanh) + layer2 reduce.
// Bit-rotate LDS swizzle: phys(g) = (g&~15)|((g>>1)&7)|((g&1)<<3) -> bank-quad
// = g[3:1], so stride-2 fixed-parity reads are conflict-free at EVERY phase.
// phys(g+1) = phys(g)+8 -> odd-granule reads are offset:128 immediates.
// Tap-block loop unrolled 2x with ping-pong register pairs (no slide movs).
// ---------------------------------------------------------------------------
__device__ const int CJ_LO[24] = {0,0,0,0,0,0,0,0,0,4,4,8,12,16,20,28,36,48,64,84,108,140,184,240};
__device__ const int CJ_NB[24] = {1,1,1,1,2,2,3,3,4,4,5,6,7,9,12,15,19,25,31,41,53,65,54,40};

__device__ __forceinline__ int phys4(int g) {
    return (g & ~15) | ((g >> 1) & 7) | ((g & 1) << 3);
}

__global__ __launch_bounds__(128) void conv_kernel(
    const float* __restrict__ syn_e, const float* __restrict__ syn_i,
    const float* __restrict__ basis,
    const float* __restrict__ W_e, const float* __restrict__ W_i,
    const float* __restrict__ b1, const float* __restrict__ W2,
    float* __restrict__ sub_out)
{
    __shared__ float4 win4[464];                  // 29 16-granule blocks
    float2* win2 = reinterpret_cast<float2*>(win4);
    const int tid = threadIdx.x;
    const int tile = blockIdx.x, s = blockIdx.y, bz = blockIdx.z;
    const int t0 = tile * 512;

    const float* se = syn_e + ((size_t)bz * 20 + s) * 5000;
    const float* si = syn_i + ((size_t)bz * 20 + s) * 5000;
    for (int l = tid; l < 920; l += 128) {
        int t = t0 - 404 + l;
        float ve = 0.f, vi = 0.f;
        if ((unsigned)t < 5000u) { ve = se[t]; vi = si[t]; }
        int g = l >> 1;
        win2[2 * phys4(g) + (l & 1)] = make_float2(ve, vi);
    }
    __syncthreads();

    float z[16][4];
    #pragma unroll
    for (int h = 0; h < 16; ++h) {
        float bv = b1[s * 16 + h];
        #pragma unroll
        for (int k = 0; k < 4; ++k) z[h][k] = bv;
    }

    const int base = 4 * tid + 400;

    for (int j = 0; j < 24; ++j) {
        const float* bj = basis + j * BSTRIDE;
        const int lo = CJ_LO[j];
        const int nb = CJ_NB[j];
        float be0 = 0.f, be1 = 0.f, be2 = 0.f, be3 = 0.f;
        float bi0 = 0.f, bi1 = 0.f, bi2 = 0.f, bi3 = 0.f;

        // body: taps dd0..dd0+3 with granules V0:(jj0,1) V1:(2,3) V2:(4,5) V3:(6,7)
        auto body = [&](const float4& V0, const float4& V1,
                        const float4& V2, const float4& V3, int dd0) {
            float c0 = bj[dd0], c1 = bj[dd0 + 1], c2 = bj[dd0 + 2], c3 = bj[dd0 + 3];
            // dd=0: jj=4,5,6,7
            be0 = fmaf(c0, V2.x, be0); bi0 = fmaf(c0, V2.y, bi0);
            be1 = fmaf(c0, V2.z, be1); bi1 = fmaf(c0, V2.w, bi1);
            be2 = fmaf(c0, V3.x, be2); bi2 = fmaf(c0, V3.y, bi2);
            be3 = fmaf(c0, V3.z, be3); bi3 = fmaf(c0, V3.w, bi3);
            // dd=1: jj=3,4,5,6
            be0 = fmaf(c1, V1.z, be0); bi0 = fmaf(c1, V1.w, bi0);
            be1 = fmaf(c1, V2.x, be1); bi1 = fmaf(c1, V2.y, bi1);
            be2 = fmaf(c1, V2.z, be2); bi2 = fmaf(c1, V2.w, bi2);
            be3 = fmaf(c1, V3.x, be3); bi3 = fmaf(c1, V3.y, bi3);
            // dd=2: jj=2,3,4,5
            be0 = fmaf(c2, V1.x, be0); bi0 = fmaf(c2, V1.y, bi0);
            be1 = fmaf(c2, V1.z, be1); bi1 = fmaf(c2, V1.w, bi1);
            be2 = fmaf(c2, V2.x, be2); bi2 = fmaf(c2, V2.y, bi2);
            be3 = fmaf(c2, V2.z, be3); bi3 = fmaf(c2, V2.w, bi3);
            // dd=3: jj=1,2,3,4
            be0 = fmaf(c3, V0.z, be0); bi0 = fmaf(c3, V0.w, bi0);
            be1 = fmaf(c3, V1.x, be1); bi1 = fmaf(c3, V1.y, bi1);
            be2 = fmaf(c3, V1.z, be2); bi2 = fmaf(c3, V1.w, bi2);
            be3 = fmaf(c3, V2.x, be3); bi3 = fmaf(c3, V2.y, bi3);
        };

        int g = (base - lo) >> 1;                 // even
        int pa = phys4(g);
        int pb = phys4(g + 2);
        float4 a0 = win4[pa], a1 = win4[pa + 8];  // granules g, g+1   (V0,V1)
        float4 b0 = win4[pb], b1v = win4[pb + 8]; // granules g+2, g+3 (V2,V3)

        int d0 = lo;
        int bb = 0;
        for (; bb + 2 <= nb; bb += 2) {
            body(a0, a1, b0, b1v, d0);
            int pn = phys4(g - 2);
            b0 = win4[pn]; b1v = win4[pn + 8];    // fresh granules g-2, g-1
            body(b0, b1v, a0, a1, d0 + 4);
            pn = phys4(g - 4);
            a0 = win4[pn]; a1 = win4[pn + 8];     // fresh granules g-4, g-3
            g -= 4;
            d0 += 8;
        }
        if (bb < nb)
            body(a0, a1, b0, b1v, d0);

        #pragma unroll
        for (int h = 0; h < 16; ++h) {
            float we = W_e[(s * 16 + h) * 24 + j];
            float wi = W_i[(s * 16 + h) * 24 + j];
            z[h][0] = fmaf(we, be0, fmaf(wi, bi0, z[h][0]));
            z[h][1] = fmaf(we, be1, fmaf(wi, bi1, z[h][1]));
            z[h][2] = fmaf(we, be2, fmaf(wi, bi2, z[h][2]));
            z[h][3] = fmaf(we, be3, fmaf(wi, bi3, z[h][3]));
        }
    }

    float w2v[16];
    #pragma unroll
    for (int h = 0; h < 16; ++h) w2v[h] = __expf(W2[s * 16 + h]);

    #pragma unroll
    for (int k = 0; k < 4; ++k) {
        int t = t0 + 4 * tid + k;
        if (t < 5000) {
            float acc = 0.f;
            #pragma unroll
            for (int h = 0; h < 16; ++h) {
                float e2 = __expf(2.0f * z[h][k]);
                float th = 1.0f - 2.0f / (e2 + 1.0f);
                acc = fmaf(w2v[h], th, acc);
            }
            sub_out[((size_t)bz * 5000 + t) * 20 + s] = acc;
        }
    }
}

// ---------------------------------------------------------------------------
// final[b,t] = V_o + sum_s sub_out[b,t,s]
// ---------------------------------------------------------------------------
__global__ __launch_bounds__(256) void final_kernel(
    const float* __restrict__ sub_out, const float* __restrict__ V_o,
    float* __restrict__ fin)
{
    int r = blockIdx.x * 256 + threadIdx.x;
    if (r < 40000) {
        const float* p = sub_out + (size_t)r * 20;
        float a = V_o[0];
        #pragma unroll
        for (int s = 0; s < 20; ++s) a += p[s];
        fin[r] = a;
    }
}

extern "C" void kernel_launch(void* const* d_in, const int* in_sizes, int n_in,
                              void* d_out, int out_size, void* d_ws, size_t ws_size,
                              hipStream_t stream)
{
    const float* S_e     = (const float*)d_in[0];
    const float* S_i     = (const float*)d_in[1];
    const float* E_scale = (const float*)d_in[2];
    const float* I_scale = (const float*)d_in[3];
    const float* W_e     = (const float*)d_in[4];
    const float* W_i     = (const float*)d_in[5];
    const float* W2      = (const float*)d_in[6];
    const float* b1      = (const float*)d_in[7];
    const float* Ce_raw  = (const float*)d_in[8];
    const float* Ci_raw  = (const float*)d_in[9];
    const float* V_o     = (const float*)d_in[10];
    const float* temp    = (const float*)d_in[11];

    float* out     = (float*)d_out;
    float* fin     = out;              // 40000
    float* sub_out = out + 40000;      // 800000
    float* outCe   = out + 840000;     // 40000
    float* outCi   = out + 880000;     // 4000

    float* ws    = (float*)d_ws;
    float* CsT_e = ws;                 // 2048*20 = 40960 (zero-padded)
    float* CsT_i = ws + 40960;         // 256*20  = 5120  (zero-padded)
    float* basis = ws + 46080;         // 24*404  = 9696
    float* syn_e = ws + 55776;         // 800000
    float* syn_i = ws + 855776;        // 800000

    prep_kernel<<<47, 256, 0, stream>>>(Ce_raw, Ci_raw, E_scale, I_scale, temp,
                                        CsT_e, CsT_i, basis, outCe, outCi);
    syn_kernel<16><<<625, 256, 0, stream>>>(S_e, CsT_e, syn_e, 2000);
    syn_kernel<2><<<625, 256, 0, stream>>>(S_i, CsT_i, syn_i, 200);
    conv_kernel<<<dim3(10, 20, 8), 128, 0, stream>>>(syn_e, syn_i, basis,
                                                     W_e, W_i, b1, W2, sub_out);
    final_kernel<<<157, 256, 0, stream>>>(sub_out, V_o, fin);
}